// Round 1
// 2738.596 us; speedup vs baseline: 6.0719x; 6.0719x over previous
//
#include <hip/hip_runtime.h>
#include <stdint.h>

// Problem dims
#define BB 32
#define SS 128
#define TT 96
#define HH 1024
#define VV 32000

typedef short bf16x8 __attribute__((ext_vector_type(8)));
typedef float f32x4 __attribute__((ext_vector_type(4)));

__device__ inline unsigned short f2bf(float f) {
    union { float f; unsigned int i; } x; x.f = f;
    unsigned int r = x.i + 0x7fffu + ((x.i >> 16) & 1u);
    return (unsigned short)(r >> 16);
}
__device__ inline float sigmoidf_(float x) {
    float xc = fminf(fmaxf(x, -30.0f), 30.0f);
    return 1.0f / (1.0f + __expf(-xc));
}
__device__ inline float tanhf_(float x) {
    float x2 = fminf(fmaxf(2.0f * x, -30.0f), 30.0f);
    float e = __expf(x2);
    return (e - 1.0f) / (e + 1.0f);
}
// fast tanh: 1 - 2/(1+e^{2x}); inf/0-safe at the extremes, ~1ulp from rcp
__device__ inline float tanh_fast(float x) {
    float e = __expf(x + x);
    return 1.0f - 2.0f * __builtin_amdgcn_rcpf(1.0f + e);
}

// ---------------------------------------------------------------------------
// 128x128-tile GEMM: C[M,N] = A[M,K] @ B[K,N] + bias   (fp32 in/out,
// bf16 MFMA internally; A/B converted to bf16 during LDS staging)
// A rows optionally gathered: row -> gbase + gidx[row]*lda
// Requires N%128==0, K%32==0; M arbitrary (clamped loads, guarded stores)
// ---------------------------------------------------------------------------
template<bool GATHER>
__global__ __launch_bounds__(256)
void gemm128(const float* __restrict__ A, long lda,
             const int* __restrict__ gidx, const float* __restrict__ gbase,
             const float* __restrict__ Bkn, long ldb,
             const float* __restrict__ bias,
             float* __restrict__ Cout, long ldc,
             int M, int N, int K)
{
    __shared__ __align__(16) unsigned short At[128 * 32];
    __shared__ __align__(16) unsigned short Bt[128 * 32];
    const int tid = threadIdx.x;
    const int m0 = blockIdx.y * 128, n0 = blockIdx.x * 128;
    const int lane = tid & 63, wave = tid >> 6;
    const int wr = wave >> 1, wc = wave & 1;
    const int lm = lane & 15, quad = lane >> 4;

    f32x4 acc[4][4] = {};

    for (int kt = 0; kt < K; kt += 32) {
        // Stage A: fp32 -> bf16, At[row][k] row-major
#pragma unroll
        for (int i = 0; i < 2; ++i) {
            int c = i * 256 + tid;
            int row = c >> 2, col = (c & 3) << 3;
            int rg = m0 + row; if (rg > M - 1) rg = M - 1;
            const float* src;
            if (GATHER) src = gbase + (size_t)gidx[rg] * lda + kt + col;
            else        src = A + (size_t)rg * lda + kt + col;
            float4 f0 = *(const float4*)src;
            float4 f1 = *(const float4*)(src + 4);
            union { int4 v; unsigned short u[8]; } t;
            t.u[0] = f2bf(f0.x); t.u[1] = f2bf(f0.y); t.u[2] = f2bf(f0.z); t.u[3] = f2bf(f0.w);
            t.u[4] = f2bf(f1.x); t.u[5] = f2bf(f1.y); t.u[6] = f2bf(f1.z); t.u[7] = f2bf(f1.w);
            *(int4*)(At + row * 32 + col) = t.v;
        }
        // Stage B: fp32 [k][n] -> bf16 transposed Bt[n][k]
#pragma unroll
        for (int i = 0; i < 2; ++i) {
            int c = i * 256 + tid;
            int kr = c >> 4, nc = (c & 15) << 3;
            const float* src = Bkn + (size_t)(kt + kr) * ldb + n0 + nc;
            float4 f0 = *(const float4*)src;
            float4 f1 = *(const float4*)(src + 4);
            Bt[(nc + 0) * 32 + kr] = f2bf(f0.x);
            Bt[(nc + 1) * 32 + kr] = f2bf(f0.y);
            Bt[(nc + 2) * 32 + kr] = f2bf(f0.z);
            Bt[(nc + 3) * 32 + kr] = f2bf(f0.w);
            Bt[(nc + 4) * 32 + kr] = f2bf(f1.x);
            Bt[(nc + 5) * 32 + kr] = f2bf(f1.y);
            Bt[(nc + 6) * 32 + kr] = f2bf(f1.z);
            Bt[(nc + 7) * 32 + kr] = f2bf(f1.w);
        }
        __syncthreads();

        bf16x8 af[4], bfr[4];
#pragma unroll
        for (int i = 0; i < 4; ++i)
            af[i] = *(const bf16x8*)(At + (wr * 64 + i * 16 + lm) * 32 + quad * 8);
#pragma unroll
        for (int j = 0; j < 4; ++j)
            bfr[j] = *(const bf16x8*)(Bt + (wc * 64 + j * 16 + lm) * 32 + quad * 8);
#pragma unroll
        for (int i = 0; i < 4; ++i)
#pragma unroll
            for (int j = 0; j < 4; ++j)
                acc[i][j] = __builtin_amdgcn_mfma_f32_16x16x32_bf16(af[i], bfr[j], acc[i][j], 0, 0, 0);
        __syncthreads();
    }

    // Epilogue: C/D layout col=lane&15, row=quad*4+reg  [m89-verified]
#pragma unroll
    for (int i = 0; i < 4; ++i) {
        int r0 = m0 + wr * 64 + i * 16 + quad * 4;
#pragma unroll
        for (int j = 0; j < 4; ++j) {
            int col = n0 + wc * 64 + j * 16 + lm;
            float bb = bias ? bias[col] : 0.0f;
#pragma unroll
            for (int r = 0; r < 4; ++r) {
                int row = r0 + r;
                if (row < M)
                    Cout[(size_t)row * ldc + col] = acc[i][j][r] + bb;
            }
        }
    }
}

// ---------------------------------------------------------------------------
// One-time: Wout [2048][32000] fp32 -> WoutT [32000][2048] bf16
// ---------------------------------------------------------------------------
__global__ __launch_bounds__(256)
void wout_to_bt(const float* __restrict__ src, unsigned short* __restrict__ dst)
{
    __shared__ float tile[64 * 68];
    const int n0 = blockIdx.x * 64;     // over 32000
    const int k0 = blockIdx.y * 64;     // over 2048
    const int tid = threadIdx.x;
#pragma unroll
    for (int i = 0; i < 4; ++i) {
        int c = i * 256 + tid;
        int kr = c >> 4, nc = (c & 15) << 2;
        *(float4*)(&tile[kr * 68 + nc]) =
            *(const float4*)(src + (size_t)(k0 + kr) * 32000 + n0 + nc);
    }
    __syncthreads();
#pragma unroll
    for (int i = 0; i < 4; ++i) {
        int c = i * 256 + tid;
        int nr = c >> 4, kc = (c & 15) << 2;
        ushort4 o;
        o.x = f2bf(tile[(kc + 0) * 68 + nr]);
        o.y = f2bf(tile[(kc + 1) * 68 + nr]);
        o.z = f2bf(tile[(kc + 2) * 68 + nr]);
        o.w = f2bf(tile[(kc + 3) * 68 + nr]);
        *(ushort4*)(dst + (size_t)(n0 + nr) * 2048 + k0 + kc) = o;
    }
}

// elementwise fp32 -> bf16, 8 per thread
__global__ __launch_bounds__(256)
void convert_bf16(const float* __restrict__ src, unsigned short* __restrict__ dst, int n8)
{
    int i = blockIdx.x * 256 + threadIdx.x;
    if (i < n8) {
        float4 a = *(const float4*)(src + (size_t)i * 8);
        float4 b = *(const float4*)(src + (size_t)i * 8 + 4);
        union { bf16x8 v; unsigned short u[8]; } t;
        t.u[0] = f2bf(a.x); t.u[1] = f2bf(a.y); t.u[2] = f2bf(a.z); t.u[3] = f2bf(a.w);
        t.u[4] = f2bf(b.x); t.u[5] = f2bf(b.y); t.u[6] = f2bf(b.z); t.u[7] = f2bf(b.w);
        *(bf16x8*)(dst + (size_t)i * 8) = t.v;
    }
}

// ---------------------------------------------------------------------------
// Final logits GEMM (m97-style): C[3072,32000] = Abf[3072,2048] @ WoutT^T
// A bf16 [M][K], B bf16 [N][K]; global_load_lds width-16 staging; 128x128 tile.
// Grid 6144 (padded); XCD-chunked over N-panels, M fast within an XCD.
// ---------------------------------------------------------------------------
__global__ __launch_bounds__(256)
void gemm_btbf(const unsigned short* __restrict__ Abf,
               const unsigned short* __restrict__ BtN,
               const float* __restrict__ bias,
               float* __restrict__ C)
{
    const int id = blockIdx.x;
    const int xcd = id & 7, slot = id >> 3;     // slot 0..767
    const int nidx = xcd * 32 + slot / 24;      // N panel
    const int midx = slot % 24;                 // M panel
    if (nidx >= 250) return;
    const int m0 = midx << 7, n0 = nidx << 7;
    __shared__ __align__(16) unsigned short At[128 * 32];
    __shared__ __align__(16) unsigned short Bs[128 * 32];
    const int tid = threadIdx.x;
    const int lane = tid & 63, wave = tid >> 6;
    const int wr = wave >> 1, wc2 = wave & 1;
    const int lm = lane & 15, quad = lane >> 4;
    const int K = 2048;
    f32x4 acc[4][4] = {};

    for (int kt = 0; kt < K; kt += 32) {
#pragma unroll
        for (int i = 0; i < 2; ++i) {
            int L = wave * 128 + i * 64 + lane;     // 0..511
            int row = L >> 2, col = (L & 3) << 3;
            const unsigned short* ga = Abf + (size_t)(m0 + row) * K + kt + col;
            const unsigned short* gb = BtN + (size_t)(n0 + row) * K + kt + col;
            __builtin_amdgcn_global_load_lds(
                (const __attribute__((address_space(1))) void*)ga,
                (__attribute__((address_space(3))) void*)(At + (size_t)L * 8), 16, 0, 0);
            __builtin_amdgcn_global_load_lds(
                (const __attribute__((address_space(1))) void*)gb,
                (__attribute__((address_space(3))) void*)(Bs + (size_t)L * 8), 16, 0, 0);
        }
        __syncthreads();

        bf16x8 af[4], bfr[4];
#pragma unroll
        for (int i = 0; i < 4; ++i)
            af[i] = *(const bf16x8*)(At + (wr * 64 + i * 16 + lm) * 32 + quad * 8);
#pragma unroll
        for (int j = 0; j < 4; ++j)
            bfr[j] = *(const bf16x8*)(Bs + (wc2 * 64 + j * 16 + lm) * 32 + quad * 8);
#pragma unroll
        for (int i = 0; i < 4; ++i)
#pragma unroll
            for (int j = 0; j < 4; ++j)
                acc[i][j] = __builtin_amdgcn_mfma_f32_16x16x32_bf16(af[i], bfr[j], acc[i][j], 0, 0, 0);
        __syncthreads();
    }

#pragma unroll
    for (int i = 0; i < 4; ++i) {
        int r0 = m0 + wr * 64 + i * 16 + quad * 4;
#pragma unroll
        for (int j = 0; j < 4; ++j) {
            int colg = n0 + wc2 * 64 + j * 16 + lm;
            float bb = bias[colg];
#pragma unroll
            for (int r = 0; r < 4; ++r)
                C[(size_t)(r0 + r) * 32000 + colg] = acc[i][j][r] + bb;
        }
    }
}

// ---------------------------------------------------------------------------
// GRU step (only thing left in the sequential loop):
// h_next = GRU(h_cur, GI[:,t,:]); writes h into combined[:,t,0:H]
// Reads Whh DIRECTLY ([1024][3072], coalesced float4 along j).
// 256 blocks = 8 b-groups(4 b each) x 32 j-chunks(32 j each), XCD-chunked so
// each XCD keeps its 1.6MB Whh slice L2-resident. Interleaved k-split (k =
// kh + 32*kk) keeps the LDS h-broadcast conflict-free.
// ---------------------------------------------------------------------------
__global__ __launch_bounds__(256)
void gru_step2(const float* __restrict__ hcur, float* __restrict__ hnext,
               const float* __restrict__ GI, const float* __restrict__ Whh,
               const float* __restrict__ bhh, float* __restrict__ combined,
               int t)
{
    __shared__ float hl[4][1024];
    __shared__ float red[4][4][3][32];    // [wave][b][gate][j-local]
    const int id = blockIdx.x;
    const int xcd = id & 7, slot = id >> 3;     // slot 0..31
    const int jc = (xcd << 2) | (slot & 3);     // 0..31  (XCD-local Whh slice)
    const int bg = slot >> 2;                   // 0..7
    const int b0 = bg << 2;
    const int tid = threadIdx.x;
#pragma unroll
    for (int i = 0; i < 4; ++i) {
        int c = i * 256 + tid;                  // 0..1023
        int bb = c >> 8, hh = (c & 255) << 2;
        *(float4*)(&hl[bb][hh]) = *(const float4*)(hcur + (size_t)(b0 + bb) * 1024 + hh);
    }
    __syncthreads();

    const int jq = tid & 7;            // 4 j's each
    const int kh = tid >> 3;           // 0..31 k-split
    const int j = jc * 32 + jq * 4;
    const int lane = tid & 63, wave = tid >> 6;
    float acc[4][3][4] = {};
    const float* wbase = Whh + j;
    for (int kk = 0; kk < 32; ++kk) {
        int k = kh + (kk << 5);                 // interleaved
        const float* wrp = wbase + (size_t)k * 3072;
        float4 w0 = *(const float4*)(wrp);
        float4 w1 = *(const float4*)(wrp + 1024);
        float4 w2 = *(const float4*)(wrp + 2048);
#pragma unroll
        for (int bb = 0; bb < 4; ++bb) {
            float h = hl[bb][k];
            acc[bb][0][0] += w0.x * h; acc[bb][0][1] += w0.y * h;
            acc[bb][0][2] += w0.z * h; acc[bb][0][3] += w0.w * h;
            acc[bb][1][0] += w1.x * h; acc[bb][1][1] += w1.y * h;
            acc[bb][1][2] += w1.z * h; acc[bb][1][3] += w1.w * h;
            acc[bb][2][0] += w2.x * h; acc[bb][2][1] += w2.y * h;
            acc[bb][2][2] += w2.z * h; acc[bb][2][3] += w2.w * h;
        }
    }
    // reduce the 8 kh's living in this wave (lane bits 3,4,5)
#pragma unroll
    for (int bb = 0; bb < 4; ++bb)
#pragma unroll
        for (int g = 0; g < 3; ++g)
#pragma unroll
            for (int x = 0; x < 4; ++x) {
                float v = acc[bb][g][x];
                v += __shfl_xor(v, 8);
                v += __shfl_xor(v, 16);
                v += __shfl_xor(v, 32);
                acc[bb][g][x] = v;
            }
    if ((lane & 56) == 0) {                     // lane 0..7 (kh-local 0)
#pragma unroll
        for (int bb = 0; bb < 4; ++bb)
#pragma unroll
            for (int g = 0; g < 3; ++g) {
                float4 v; v.x = acc[bb][g][0]; v.y = acc[bb][g][1];
                v.z = acc[bb][g][2]; v.w = acc[bb][g][3];
                *(float4*)(&red[wave][bb][g][jq * 4]) = v;
            }
    }
    __syncthreads();
    if (tid < 128) {
        int bb = tid >> 5, jl = tid & 31;
        int jg = jc * 32 + jl;
        float g0 = red[0][bb][0][jl] + red[1][bb][0][jl] + red[2][bb][0][jl] + red[3][bb][0][jl];
        float g1 = red[0][bb][1][jl] + red[1][bb][1][jl] + red[2][bb][1][jl] + red[3][bb][1][jl];
        float g2 = red[0][bb][2][jl] + red[1][bb][2][jl] + red[2][bb][2][jl] + red[3][bb][2][jl];
        int bglob = b0 + bb;
        size_t gir = ((size_t)bglob * TT + t) * 3072;
        float ir = GI[gir + jg], iz = GI[gir + 1024 + jg], inn = GI[gir + 2048 + jg];
        float hr = g0 + bhh[jg], hz = g1 + bhh[1024 + jg], hn = g2 + bhh[2048 + jg];
        float r = sigmoidf_(ir + hr);
        float z = sigmoidf_(iz + hz);
        float n = tanhf_(inn + r * hn);
        float hv = (1.0f - z) * n + z * hl[bb][jg];
        hnext[(size_t)bglob * 1024 + jg] = hv;
        combined[((size_t)bglob * TT + t) * 2048 + jg] = hv;
    }
}

// ---------------------------------------------------------------------------
// Batched attention over all (b,t) — hoisted out of the loop (ctx never feeds
// the recurrence). Block = (b, 8 t's). scores=tanh(qw+vw)@wc+bc; softmax;
// ctx = w @ values -> combined[:,t,H:2H].
// ---------------------------------------------------------------------------
__global__ __launch_bounds__(256)
void attn_all(const float* __restrict__ qwAll, const float* __restrict__ vw,
              const float* __restrict__ values, const float* __restrict__ wc,
              const float* __restrict__ bc, const int* __restrict__ mask,
              float* __restrict__ combined)
{
    __shared__ float qwl[8][1024];
    __shared__ float vwl[8][1028];    // pad 4: conflict-free row spread
    __shared__ float wcl[1024];
    __shared__ float sc[8][132];
    __shared__ int maskl[128];
    const int b = blockIdx.x, t0 = blockIdx.y * 8;
    const int tid = threadIdx.x;
#pragma unroll
    for (int i = 0; i < 8; ++i) {
        int c = i * 256 + tid;                  // 0..2047
        int tt = c >> 8, hh = (c & 255) << 2;
        *(float4*)(&qwl[tt][hh]) =
            *(const float4*)(qwAll + ((size_t)b * TT + t0 + tt) * 1024 + hh);
    }
#pragma unroll
    for (int i = 0; i < 4; ++i) { int c = i * 256 + tid; wcl[c] = wc[c]; }
    if (tid < 128) maskl[tid] = mask[b * SS + tid];

    const int q = tid & 3, p = tid >> 2;
    const int s8 = p & 7, t8 = p >> 3;
    const float bc0 = bc[0];

    for (int stile = 0; stile < 16; ++stile) {
        __syncthreads();     // vwl safe to overwrite; covers initial staging too
#pragma unroll
        for (int i = 0; i < 8; ++i) {
            int c = i * 256 + tid;
            int sr = c >> 8, hh = (c & 255) << 2;
            *(float4*)(&vwl[sr][hh]) =
                *(const float4*)(vw + ((size_t)b * SS + stile * 8 + sr) * 1024 + hh);
        }
        __syncthreads();
        float part = 0.f;
        const float* qp = &qwl[t8][q * 256];
        const float* vp = &vwl[s8][q * 256];
        const float* wp = &wcl[q * 256];
#pragma unroll 4
        for (int i = 0; i < 256; i += 4) {
            float4 qv = *(const float4*)(qp + i);
            float4 vv = *(const float4*)(vp + i);
            float4 wv = *(const float4*)(wp + i);
            part += tanh_fast(qv.x + vv.x) * wv.x;
            part += tanh_fast(qv.y + vv.y) * wv.y;
            part += tanh_fast(qv.z + vv.z) * wv.z;
            part += tanh_fast(qv.w + vv.w) * wv.w;
        }
        part += __shfl_xor(part, 1);
        part += __shfl_xor(part, 2);
        if (q == 0) {
            int s = stile * 8 + s8;
            float v = part + bc0;
            if (maskl[s] == 0) v -= 1e30f;
            sc[t8][s] = v;
        }
    }
    __syncthreads();
    // softmax: 32 lanes per t
    {
        int tt = tid >> 5, l = tid & 31;
        float v0 = sc[tt][l], v1 = sc[tt][l + 32], v2 = sc[tt][l + 64], v3 = sc[tt][l + 96];
        float m = fmaxf(fmaxf(v0, v1), fmaxf(v2, v3));
#pragma unroll
        for (int off = 16; off; off >>= 1) m = fmaxf(m, __shfl_xor(m, off));
        float e0 = __expf(v0 - m), e1 = __expf(v1 - m), e2 = __expf(v2 - m), e3 = __expf(v3 - m);
        float s4 = e0 + e1 + e2 + e3;
#pragma unroll
        for (int off = 16; off; off >>= 1) s4 += __shfl_xor(s4, off);
        float inv = __builtin_amdgcn_rcpf(s4);
        sc[tt][l] = e0 * inv; sc[tt][l + 32] = e1 * inv;
        sc[tt][l + 64] = e2 * inv; sc[tt][l + 96] = e3 * inv;
    }
    __syncthreads();
    // ctx: [8,128] @ values[b][128][1024]
    const int j0 = tid << 2;
    float4 acc[8] = {};
    const float* vp2 = values + (size_t)b * SS * 1024 + j0;
    for (int si = 0; si < 128; ++si) {
        float4 v = *(const float4*)(vp2 + (size_t)si * 1024);
        float w0 = sc[0][si], w1 = sc[1][si], w2 = sc[2][si], w3 = sc[3][si];
        float w4 = sc[4][si], w5 = sc[5][si], w6 = sc[6][si], w7 = sc[7][si];
        acc[0].x += w0 * v.x; acc[0].y += w0 * v.y; acc[0].z += w0 * v.z; acc[0].w += w0 * v.w;
        acc[1].x += w1 * v.x; acc[1].y += w1 * v.y; acc[1].z += w1 * v.z; acc[1].w += w1 * v.w;
        acc[2].x += w2 * v.x; acc[2].y += w2 * v.y; acc[2].z += w2 * v.z; acc[2].w += w2 * v.w;
        acc[3].x += w3 * v.x; acc[3].y += w3 * v.y; acc[3].z += w3 * v.z; acc[3].w += w3 * v.w;
        acc[4].x += w4 * v.x; acc[4].y += w4 * v.y; acc[4].z += w4 * v.z; acc[4].w += w4 * v.w;
        acc[5].x += w5 * v.x; acc[5].y += w5 * v.y; acc[5].z += w5 * v.z; acc[5].w += w5 * v.w;
        acc[6].x += w6 * v.x; acc[6].y += w6 * v.y; acc[6].z += w6 * v.z; acc[6].w += w6 * v.w;
        acc[7].x += w7 * v.x; acc[7].y += w7 * v.y; acc[7].z += w7 * v.z; acc[7].w += w7 * v.w;
    }
#pragma unroll
    for (int tt = 0; tt < 8; ++tt)
        *(float4*)(combined + ((size_t)b * TT + t0 + tt) * 2048 + 1024 + j0) = acc[tt];
}

__global__ __launch_bounds__(256)
void copy_h_final(const float* __restrict__ h, float* __restrict__ out)
{
    int i = blockIdx.x * 256 + threadIdx.x;
    out[i] = h[i];
}

// ---------------------------------------------------------------------------
extern "C" void kernel_launch(void* const* d_in, const int* in_sizes, int n_in,
                              void* d_out, int out_size, void* d_ws, size_t ws_size,
                              hipStream_t stream)
{
    const float* enc_out = (const float*)d_in[0];   // [B,S,2H]
    const float* enc_hid = (const float*)d_in[1];   // [B,2H]
    const int*   maskp   = (const int*)d_in[2];     // [B,S]
    const int*   tgt     = (const int*)d_in[3];     // [B,T]
    const float* emb     = (const float*)d_in[4];   // [V,H]
    const float* Wq      = (const float*)d_in[5];
    const float* bq      = (const float*)d_in[6];
    const float* Wv      = (const float*)d_in[7];
    const float* bv      = (const float*)d_in[8];
    const float* wc      = (const float*)d_in[9];
    const float* bc      = (const float*)d_in[10];
    const float* Wih     = (const float*)d_in[11];
    const float* bih     = (const float*)d_in[12];
    const float* Whh     = (const float*)d_in[13];
    const float* bhh     = (const float*)d_in[14];
    const float* Wproj   = (const float*)d_in[15];
    const float* bproj   = (const float*)d_in[16];
    const float* Wout    = (const float*)d_in[17];
    const float* bout    = (const float*)d_in[18];

    // Workspace layout
    char* ws = (char*)d_ws;
    float* values   = (float*)ws; ws += (size_t)4096 * 1024 * 4;   // [B*S,H]
    float* vw       = (float*)ws; ws += (size_t)4096 * 1024 * 4;   // [B*S,H]
    float* GI       = (float*)ws; ws += (size_t)3072 * 3072 * 4;   // [B*T,3H]
    float* combined = (float*)ws; ws += (size_t)3072 * 2048 * 4;   // [B*T,2H]
    float* hbuf     = (float*)ws; ws += (size_t)2 * 32 * 1024 * 4;
    float* qwAll    = (float*)ws; ws += (size_t)3072 * 1024 * 4;   // [B*T,H]
    unsigned short* Abf   = (unsigned short*)ws; ws += (size_t)3072 * 2048 * 2;
    unsigned short* WoutT = (unsigned short*)ws; ws += (size_t)32000 * 2048 * 2;
    const bool fast = ws_size >= (size_t)(ws - (char*)d_ws);

    // One-time Wout transpose+convert (independent; HBM-bound ~70us)
    if (fast)
        wout_to_bt<<<dim3(500, 32), 256, 0, stream>>>(Wout, WoutT);

    // values = enc_out @ Wproj + bproj   [4096,2048]@[2048,1024]
    gemm128<false><<<dim3(8, 32), 256, 0, stream>>>(
        enc_out, 2048, nullptr, nullptr, Wproj, 1024, bproj, values, 1024, 4096, 1024, 2048);
    // h0 = enc_hid @ Wproj + bproj
    gemm128<false><<<dim3(8, 1), 256, 0, stream>>>(
        enc_hid, 2048, nullptr, nullptr, Wproj, 1024, bproj, hbuf, 1024, 32, 1024, 2048);
    // vw = values @ Wv + bv
    gemm128<false><<<dim3(8, 32), 256, 0, stream>>>(
        values, 1024, nullptr, nullptr, Wv, 1024, bv, vw, 1024, 4096, 1024, 1024);
    // GI = emb[tgt] @ Wih + bih   [3072,1024]@[1024,3072]
    gemm128<true><<<dim3(24, 24), 256, 0, stream>>>(
        nullptr, 1024, tgt, emb, Wih, 3072, bih, GI, 3072, 3072, 3072, 1024);

    // Sequential recurrence: GRU only (attention hoisted out)
    for (int t = 0; t < TT; ++t) {
        const float* hc = hbuf + (size_t)(t & 1) * 32768;
        float*       hn = hbuf + (size_t)((t + 1) & 1) * 32768;
        gru_step2<<<256, 256, 0, stream>>>(hc, hn, GI, Whh, bhh, combined, t);
    }

    // qwAll = H_all @ Wq + bq   (A = combined[:, 0:H], lda=2048)
    gemm128<false><<<dim3(8, 24), 256, 0, stream>>>(
        combined, 2048, nullptr, nullptr, Wq, 1024, bq, qwAll, 1024, 3072, 1024, 1024);

    // batched attention for all (b,t)
    attn_all<<<dim3(32, 12), 256, 0, stream>>>(
        qwAll, vw, values, wc, bc, maskp, combined);

    // logits = combined @ Wout + bout
    if (fast) {
        convert_bf16<<<3072, 256, 0, stream>>>(combined, Abf, 3072 * 2048 / 8);
        gemm_btbf<<<6144, 256, 0, stream>>>(Abf, WoutT, bout, (float*)d_out);
    } else {
        gemm128<false><<<dim3(250, 24), 256, 0, stream>>>(
            combined, 2048, nullptr, nullptr, Wout, 32000, bout, (float*)d_out, 32000,
            3072, 32000, 2048);
    }

    // h_final (after t=95, result is in hbuf[0])
    copy_h_final<<<128, 256, 0, stream>>>(hbuf, (float*)d_out + (size_t)BB * TT * VV);
}